// Round 7
// baseline (161.484 us; speedup 1.0000x reference)
//
#include <hip/hip_runtime.h>

#define HH 480
#define WW 640
#define BB 4
#define PPP 4
#define NN 262144
#define HWPX (HH * WW)

// scatter tiling: 24x80 tiles, 20 rows x 8 cols per batch
#define TH 24
#define TW 80
#define TXN 8                // tiles per row
#define TPB 160              // tiles per batch (20x8)
#define NT (BB * TPB)        // 640 tiles total
#define BNDC (TW + TH - 1)   // 103 boundary cells
#define HALC (TW + 1 + TH)   // 105 halo cells
#define BND_PITCH 104
#define HALO_PITCH 108
#define CAP 2048             // bucket capacity per tile (mean ~1638, ~10 sigma)
#define CAPSHIFT 11

// flow kernel: 1 quad (4 px) per thread, 300 blocks per plane, 16 planes
#define QPR 160              // quads per row
#define QPP 76800            // quads per plane
#define FBLK 4800            // total blocks

__device__ __forceinline__ float charb6(float a) { return sqrtf(a * a + 1e-6f); }

// ---------------- block reduce helper (256 threads) ----------------
__device__ __forceinline__ float block_reduce_256(float v, float* smem) {
#pragma unroll
    for (int off = 32; off > 0; off >>= 1) v += __shfl_down(v, off, 64);
    int lane = threadIdx.x & 63;
    int wid = threadIdx.x >> 6;
    if (lane == 0) smem[wid] = v;
    __syncthreads();
    float r = 0.0f;
    if (threadIdx.x == 0) r = smem[0] + smem[1] + smem[2] + smem[3];
    __syncthreads();
    return r;  // valid only on thread 0
}

// ---------------- Bin: counting-sort events into per-tile buckets ----------
__global__ void bin_kernel(const float* __restrict__ ev,
                           const float* __restrict__ pol,
                           const float* __restrict__ ts,
                           float4* __restrict__ bucket,
                           unsigned* __restrict__ gcnt) {
    __shared__ unsigned hist[TPB];
    __shared__ unsigned basebuf[TPB];
    int tid = threadIdx.x;
    if (tid < TPB) hist[tid] = 0;
    __syncthreads();

    int start = blockIdx.x * 1024;  // block covers events [start, start+1024)
    int b = start >> 18;            // all in one batch (1024 | N)
    const float2* ev2 = (const float2*)ev;

    float yv[4], xv[4], vv[4];
    int tt[4];
    unsigned rr[4];
#pragma unroll
    for (int k = 0; k < 4; ++k) {
        int gidx = start + tid + k * 256;
        int n = gidx & (NN - 1);
        float2 e = ev2[gidx];
        float y = e.x, x = e.y;
        int iy = (int)floorf(y), ix = (int)floorf(x);
        int t = (iy / TH) * TXN + (ix / TW);
        float p0 = pol[((size_t)b * 4 * NN + n) * 2];
        float tsv = ts[(size_t)b * 4 * NN + n];
        float nt = 1.0f - fabsf(1.0f - tsv);
        float v = nt * nt;
        yv[k] = y;
        xv[k] = x;
        vv[k] = (p0 > 0.5f) ? v : -v;
        tt[k] = t;
        rr[k] = atomicAdd(&hist[t], 1u);
    }
    __syncthreads();
    if (tid < TPB) basebuf[tid] = atomicAdd(&gcnt[b * TPB + tid], hist[tid]);
    __syncthreads();

#pragma unroll
    for (int k = 0; k < 4; ++k) {
        unsigned slot = basebuf[tt[k]] + rr[k];
        if (slot < CAP)
            bucket[((size_t)(b * TPB + tt[k]) << CAPSHIFT) + slot] =
                make_float4(yv[k], xv[k], vv[k], 0.0f);
    }
}

// ---------------- Tile accumulate: LDS scatter + in-kernel focus -----------
__global__ __launch_bounds__(256, 4) void tile_accum(
        const float4* __restrict__ bucket, const unsigned* __restrict__ gcnt,
        float* __restrict__ bnd, float* __restrict__ halo,
        float* __restrict__ acc) {
    __shared__ float T[2][TH + 1][TW + 1];
    __shared__ float smem[4];
    int tid = threadIdx.x;
    int l = blockIdx.x;
    int b = l / TPB;
    int t = l - b * TPB;
    int row0 = (t / TXN) * TH;
    int col0 = (t % TXN) * TW;

    for (int i = tid; i < 2 * (TH + 1) * (TW + 1); i += 256) ((float*)T)[i] = 0.0f;
    __syncthreads();

    unsigned cnt = gcnt[l];
    if (cnt > CAP) cnt = CAP;
    const float4* bk = bucket + ((size_t)l << CAPSHIFT);

    for (unsigned j = tid; j < cnt; j += 256) {
        float4 r = bk[j];
        float y = r.x, x = r.y, v = r.z;
        float fy = floorf(y), fx = floorf(x);
        int ly = (int)fy - row0;
        int lx = (int)fx - col0;
        unsigned u = __float_as_uint(v);
        int plane = u >> 31;
        float a = __uint_as_float(u & 0x7fffffffu);
        float wy1 = y - fy, wy0 = 1.0f - wy1;
        float wx1 = x - fx, wx0 = 1.0f - wx1;
        float* Tp = &T[plane][ly][lx];
        atomicAdd(Tp, a * wy0 * wx0);
        atomicAdd(Tp + 1, a * wy0 * wx1);
        atomicAdd(Tp + (TW + 1), a * wy1 * wx0);
        atomicAdd(Tp + (TW + 2), a * wy1 * wx1);
    }
    __syncthreads();

    // focus over final cells: rows 1..TH-1, cols 1..TW-1
    float a1 = 0.0f, a2 = 0.0f;
    for (int i = tid; i < (TH - 1) * (TW - 1); i += 256) {
        int r = 1 + i / (TW - 1);
        int c = 1 + i % (TW - 1);
        float ps = T[0][r][c], ns = T[1][r][c];
        a1 += ps * ps + ns * ns;
        a2 += (ps > 0.0f || ns > 0.0f) ? 1.0f : 0.0f;
    }

    // boundary cells: row 0 (TW cols), col 0 (rows 1..TH-1)
    for (int i = tid; i < 2 * BNDC; i += 256) {
        int p = i / BNDC, q = i - p * BNDC;
        float v = (q < TW) ? T[p][0][q] : T[p][q - (TW - 1)][0];
        bnd[((size_t)l * 2 + p) * BND_PITCH + q] = v;
    }
    // halo strips: row TH (TW+1 cols incl corner), col TW (rows 0..TH-1)
    for (int i = tid; i < 2 * HALC; i += 256) {
        int p = i / HALC, q = i - p * HALC;
        float v = (q < TW + 1) ? T[p][TH][q] : T[p][q - (TW + 1)][TW];
        halo[((size_t)l * 2 + p) * HALO_PITCH + q] = v;
    }

    float r1 = block_reduce_256(a1, smem);
    float r2 = block_reduce_256(a2, smem);
    if (tid == 0) {
        atomicAdd(&acc[b], r1);
        atomicAdd(&acc[32 + b], r2);
    }
}

// ---------------- Boundary merge: finish focus on tile row-0/col-0 --------
__global__ void boundary_merge(const float* __restrict__ bnd,
                               const float* __restrict__ halo,
                               float* __restrict__ acc) {
    __shared__ float smem[4];
    int l = blockIdx.x;
    int tid = threadIdx.x;
    int b = l / TPB;
    int t = l - b * TPB;
    int ty = t / TXN, tx = t - ty * TXN;

    float a1 = 0.0f, a2 = 0.0f;
    if (tid < BNDC) {
        float v[2];
#pragma unroll
        for (int p = 0; p < 2; ++p) {
            float s = bnd[((size_t)l * 2 + p) * BND_PITCH + tid];
            if (tid < TW) {
                // pixel (row0, col0+tid)
                if (ty > 0) s += halo[((size_t)(l - TXN) * 2 + p) * HALO_PITCH + tid];
                if (tid == 0) {
                    if (ty > 0 && tx > 0)
                        s += halo[((size_t)(l - TXN - 1) * 2 + p) * HALO_PITCH + TW];
                    if (tx > 0)
                        s += halo[((size_t)(l - 1) * 2 + p) * HALO_PITCH + (TW + 1) + 0];
                }
            } else {
                int r = tid - (TW - 1);  // 1..TH-1: pixel (row0+r, col0)
                if (tx > 0) s += halo[((size_t)(l - 1) * 2 + p) * HALO_PITCH + (TW + 1) + r];
            }
            v[p] = s;
        }
        a1 = v[0] * v[0] + v[1] * v[1];
        a2 = (v[0] > 0.0f || v[1] > 0.0f) ? 1.0f : 0.0f;
    }
    float r1 = block_reduce_256(a1, smem);
    float r2 = block_reduce_256(a2, smem);
    if (tid == 0) {
        atomicAdd(&acc[b], r1);
        atomicAdd(&acc[32 + b], r2);
    }
}

// ---------------- Fused flow kernel: no LDS, direct cached reads -----------
// 4800 blocks, 1 quad (4 px) per thread. XCD-chunked swizzle: each XCD owns
// 2 planes (fx+fy+next ~4.8MB, ~L2-resident). Spatial diffs from L1-local
// loads; temporal self-warp gathers from next plane (L2).
__global__ __launch_bounds__(256) void flow_fused(const float* __restrict__ flow,
                                                  float* __restrict__ acc) {
    __shared__ float smem[4];
    int tid = threadIdx.x;
    int bid = blockIdx.x;
    int nb = (bid & 7) * (FBLK / 8) + (bid >> 3);  // bijective, 4800 % 8 == 0
    int qid = nb * 256 + tid;
    int plane = qid / QPP;            // 0..15, uniform per block (QPP%256==0... 300 blocks/plane)
    int rem = qid - plane * QPP;
    int h = rem / QPR;
    int qc = rem - h * QPR;
    int c = qc * 4;
    int b = plane >> 2, p = plane & 3;

    const float* fx = flow + ((size_t)plane * 2) * HWPX;
    const float* fy = fx + HWPX;
    int i = h * WW + c;

    bool he = (h < HH - 1);
    bool last = (c + 4 >= WW);

    float4 fxv = *(const float4*)(fx + i);
    float4 fyv = *(const float4*)(fy + i);
    float fxr = last ? 0.0f : fx[i + 4];
    float fyr = last ? 0.0f : fy[i + 4];
    float4 fxb = make_float4(0, 0, 0, 0), fyb = make_float4(0, 0, 0, 0);
    float fxbr = 0.0f, fybr = 0.0f;
    if (he) {
        fxb = *(const float4*)(fx + i + WW);
        fyb = *(const float4*)(fy + i + WW);
        if (!last) {
            fxbr = fx[i + WW + 4];
            fybr = fy[i + WW + 4];
        }
    }

    float X[5] = {fxv.x, fxv.y, fxv.z, fxv.w, fxr};
    float Y[5] = {fyv.x, fyv.y, fyv.z, fyv.w, fyr};
    float XB[5] = {fxb.x, fxb.y, fxb.z, fxb.w, fxbr};
    float YB[5] = {fyb.x, fyb.y, fyb.z, fyb.w, fybr};

    const float wdx = 1.0f / ((float)HH * (float)(WW - 1) * (float)PPP * 4.0f);
    const float wdy = 1.0f / ((float)(HH - 1) * (float)WW * (float)PPP * 4.0f);
    const float wdd = 1.0f / ((float)(HH - 1) * (float)(WW - 1) * (float)PPP * 4.0f);

    bool do_temp = (p < PPP - 1);
    const float* fx_n = fx + 2 * HWPX;
    const float* fy_n = fx_n + HWPX;

    float a_sp = 0.0f, a_dt = 0.0f, a_m = 0.0f;

#pragma unroll
    for (int k = 0; k < 4; ++k) {
        int w = c + k;
        bool we = (w < WW - 1);
        float fx00 = X[k], fx01 = X[k + 1];
        float fy00 = Y[k], fy01 = Y[k + 1];
        if (we) a_sp += wdx * (charb6(fx00 - fx01) + charb6(fy00 - fy01));
        if (he) {
            float fx10 = XB[k], fx11 = XB[k + 1];
            float fy10 = YB[k], fy11 = YB[k + 1];
            a_sp += wdy * (charb6(fx00 - fx10) + charb6(fy00 - fy10));
            if (we) {
                a_sp += wdd * (charb6(fx00 - fx11) + charb6(fy00 - fy11));
                a_sp += wdd * (charb6(fx10 - fx01) + charb6(fy10 - fy01));
            }
        }
        if (do_temp) {
            float cy = fy00, cx = fx00;
            float wy = (float)h + cy;
            float wx = (float)w + cx;
            bool inb = (wy >= 0.0f) && (wy <= (float)(HH - 1)) &&
                       (wx >= 0.0f) && (wx <= (float)(WW - 1));
            a_m += inb ? 1.0f : 0.0f;
            if (inb) {
                float y0f = floorf(wy);
                float x0f = floorf(wx);
                float wy1 = wy - y0f, wy0 = 1.0f - wy1;
                float wx1 = wx - x0f, wx0 = 1.0f - wx1;
                int y0i = (int)fminf(fmaxf(y0f, 0.0f), (float)(HH - 1));
                int y1i = (int)fminf(fmaxf(y0f + 1.0f, 0.0f), (float)(HH - 1));
                int x0i = (int)fminf(fmaxf(x0f, 0.0f), (float)(WW - 1));
                int x1i = (int)fminf(fmaxf(x0f + 1.0f, 0.0f), (float)(WW - 1));
                float w00 = wy0 * wx0, w01 = wy0 * wx1, w10 = wy1 * wx0, w11 = wy1 * wx1;
                int i00 = y0i * WW + x0i, i01 = y0i * WW + x1i;
                int i10 = y1i * WW + x0i, i11 = y1i * WW + x1i;
                float wfy = w00 * fy_n[i00] + w01 * fy_n[i01] +
                            w10 * fy_n[i10] + w11 * fy_n[i11];
                float wfx = w00 * fx_n[i00] + w01 * fx_n[i01] +
                            w10 * fx_n[i10] + w11 * fx_n[i11];
                float dy = cy - wfy;
                float dx = cx - wfx;
                a_dt += sqrtf(dy * dy + 1e-9f) + sqrtf(dx * dx + 1e-9f);
            }
        }
    }

    float r_sp = block_reduce_256(a_sp, smem);
    float r_dt = block_reduce_256(a_dt, smem);
    float r_m = block_reduce_256(a_m, smem);
    if (tid == 0) {
        atomicAdd(&acc[4 + plane], r_sp);  // per-plane slot: 4..19
        if (do_temp) {
            int bp = b * (PPP - 1) + p;
            atomicAdd(&acc[20 + bp], r_dt);
            atomicAdd(&acc[52 + bp], r_m);
        }
    }
}

// ---------------- Finalize ----------------
__global__ void finalize_kernel(const float* __restrict__ acc,
                                float* __restrict__ out) {
    if (threadIdx.x == 0) {
        float loss = 0.0f;
        for (int b = 0; b < BB; ++b) loss += acc[b] / (acc[32 + b] + 1e-9f);
        for (int r = 4; r < 20; ++r) loss += acc[r];
        float tl = 0.0f;
        for (int r = 20; r < 32; ++r) tl += acc[r] / (acc[32 + r] + 1e-9f);
        loss += tl / (float)(PPP - 1);
        out[0] = loss;
    }
}

extern "C" void kernel_launch(void* const* d_in, const int* in_sizes, int n_in,
                              void* d_out, int out_size, void* d_ws, size_t ws_size,
                              hipStream_t stream) {
    const float* ev = (const float*)d_in[0];    // (B,N,2)
    const float* pol = (const float*)d_in[1];   // (B,4N,2)
    const float* ts = (const float*)d_in[2];    // (B,4N,1)
    const float* flow = (const float*)d_in[3];  // (B,P,2,H,W)
    float* out = (float*)d_out;
    float* ws = (float*)d_ws;

    float* acc = ws;                                   // 64 f32
    unsigned* gcnt = (unsigned*)(ws + 64);             // NT u32
    float4* bucket = (float4*)(ws + 64 + NT);          // NT*CAP float4
    float* bnd = (float*)(bucket + ((size_t)NT << CAPSHIFT));
    float* halo = bnd + (size_t)NT * 2 * BND_PITCH;

    hipMemsetAsync(ws, 0, (64 + NT) * sizeof(float), stream);

    bin_kernel<<<(BB * NN) / 1024, 256, 0, stream>>>(ev, pol, ts, bucket, gcnt);
    tile_accum<<<NT, 256, 0, stream>>>(bucket, gcnt, bnd, halo, acc);
    boundary_merge<<<NT, 256, 0, stream>>>(bnd, halo, acc);

    flow_fused<<<FBLK, 256, 0, stream>>>(flow, acc);

    finalize_kernel<<<1, 64, 0, stream>>>(acc, out);
}

// Round 8
// 145.390 us; speedup vs baseline: 1.1107x; 1.1107x over previous
//
#include <hip/hip_runtime.h>

#define HH 480
#define WW 640
#define BB 4
#define PPP 4
#define NN 262144
#define HWPX (HH * WW)

// scatter tiling: 24x80 tiles, 20 rows x 8 cols per batch
#define TH 24
#define TW 80
#define TXN 8                // tiles per row
#define TPB 160              // tiles per batch (20x8)
#define NT (BB * TPB)        // 640 tiles total
#define BNDC (TW + TH - 1)   // 103 boundary cells
#define HALC (TW + 1 + TH)   // 105 halo cells
#define BND_PITCH 104
#define HALO_PITCH 108
#define CAP 2048             // bucket capacity per tile (mean ~1638, ~10 sigma)
#define CAPSHIFT 11

// flow decomposition: 2400 units; unit = 2048 px of one plane; 150 units/plane
#define FUNITS 2400
#define FU_A 960             // units in K1
#define FU_B 1440            // units in K2
#define NBIN 1024            // bin blocks in K1

__device__ __forceinline__ float charb6(float a) { return sqrtf(a * a + 1e-6f); }

// ---------------- block reduce helper (256 threads) ----------------
__device__ __forceinline__ float block_reduce_256(float v, float* smem) {
#pragma unroll
    for (int off = 32; off > 0; off >>= 1) v += __shfl_down(v, off, 64);
    int lane = threadIdx.x & 63;
    int wid = threadIdx.x >> 6;
    if (lane == 0) smem[wid] = v;
    __syncthreads();
    float r = 0.0f;
    if (threadIdx.x == 0) r = smem[0] + smem[1] + smem[2] + smem[3];
    __syncthreads();
    return r;  // valid only on thread 0
}

// ---------------- Flow work unit: spat + temp for 2048 px of one plane -----
// Branchless: all gathers issued unconditionally (clamped addrs), masks
// applied arithmetically — matches reference compute-then-mask semantics.
__device__ void flow_work(int g, const float* __restrict__ flow,
                          float* __restrict__ acc, float* smem) {
    int tid = threadIdx.x;
    int plane = g / 150;
    int rem = g - plane * 150;
    int b = plane >> 2, p = plane & 3;

    const float* fx = flow + (size_t)(plane * 2) * HWPX;
    const float* fy = fx + HWPX;
    const float* fx_n = fx + 2 * HWPX;
    const float* fy_n = fx_n + HWPX;
    bool do_temp = (p < PPP - 1);

    const float wdx = 1.0f / ((float)HH * (float)(WW - 1) * (float)PPP * 4.0f);
    const float wdy = 1.0f / ((float)(HH - 1) * (float)WW * (float)PPP * 4.0f);
    const float wdd = 1.0f / ((float)(HH - 1) * (float)(WW - 1) * (float)PPP * 4.0f);

    float a_sp = 0.0f, a_dt = 0.0f, a_m = 0.0f;

#pragma unroll
    for (int q = 0; q < 2; ++q) {
        int off = rem * 2048 + q * 1024 + tid * 4;
        int h = off / WW;
        int c = off - h * WW;

        float mhe = (h < HH - 1) ? 1.0f : 0.0f;
        int ib = (h < HH - 1) ? off + WW : off;
        int ir = (c + 4 < WW) ? off + 4 : off + 3;
        int ibr = (c + 4 < WW) ? ib + 4 : ib + 3;

        float4 fxv = *(const float4*)(fx + off);
        float4 fyv = *(const float4*)(fy + off);
        float4 fxb = *(const float4*)(fx + ib);
        float4 fyb = *(const float4*)(fy + ib);
        float X[5] = {fxv.x, fxv.y, fxv.z, fxv.w, fx[ir]};
        float Y[5] = {fyv.x, fyv.y, fyv.z, fyv.w, fy[ir]};
        float XB[5] = {fxb.x, fxb.y, fxb.z, fxb.w, fx[ibr]};
        float YB[5] = {fyb.x, fyb.y, fyb.z, fyb.w, fy[ibr]};

#pragma unroll
        for (int k = 0; k < 4; ++k) {
            float mwe = (c + k < WW - 1) ? 1.0f : 0.0f;
            a_sp += mwe * wdx * (charb6(X[k] - X[k + 1]) + charb6(Y[k] - Y[k + 1]))
                  + mhe * wdy * (charb6(X[k] - XB[k]) + charb6(Y[k] - YB[k]))
                  + mhe * mwe * wdd * (charb6(X[k] - XB[k + 1]) + charb6(Y[k] - YB[k + 1])
                                     + charb6(XB[k] - X[k + 1]) + charb6(YB[k] - Y[k + 1]));
        }

        if (do_temp) {
            float msk[4], w00[4], w01[4], w10[4], w11[4];
            int i00[4], i01[4], i10[4], i11[4];
#pragma unroll
            for (int k = 0; k < 4; ++k) {
                float cy = Y[k], cx = X[k];
                float wy = (float)h + cy;
                float wx = (float)(c + k) + cx;
                msk[k] = (wy >= 0.0f && wy <= (float)(HH - 1) &&
                          wx >= 0.0f && wx <= (float)(WW - 1)) ? 1.0f : 0.0f;
                float y0f = floorf(wy), x0f = floorf(wx);
                float fy1 = wy - y0f, fx1 = wx - x0f;
                float fy0 = 1.0f - fy1, fx0 = 1.0f - fx1;
                int y0 = (int)fminf(fmaxf(y0f, 0.0f), (float)(HH - 1));
                int y1 = (int)fminf(fmaxf(y0f + 1.0f, 0.0f), (float)(HH - 1));
                int x0 = (int)fminf(fmaxf(x0f, 0.0f), (float)(WW - 1));
                int x1 = (int)fminf(fmaxf(x0f + 1.0f, 0.0f), (float)(WW - 1));
                w00[k] = fy0 * fx0; w01[k] = fy0 * fx1;
                w10[k] = fy1 * fx0; w11[k] = fy1 * fx1;
                i00[k] = y0 * WW + x0; i01[k] = y0 * WW + x1;
                i10[k] = y1 * WW + x0; i11[k] = y1 * WW + x1;
            }
            float gy00[4], gy01[4], gy10[4], gy11[4];
            float gx00[4], gx01[4], gx10[4], gx11[4];
#pragma unroll
            for (int k = 0; k < 4; ++k) {
                gy00[k] = fy_n[i00[k]]; gy01[k] = fy_n[i01[k]];
                gy10[k] = fy_n[i10[k]]; gy11[k] = fy_n[i11[k]];
            }
#pragma unroll
            for (int k = 0; k < 4; ++k) {
                gx00[k] = fx_n[i00[k]]; gx01[k] = fx_n[i01[k]];
                gx10[k] = fx_n[i10[k]]; gx11[k] = fx_n[i11[k]];
            }
#pragma unroll
            for (int k = 0; k < 4; ++k) {
                float wfy = w00[k] * gy00[k] + w01[k] * gy01[k] +
                            w10[k] * gy10[k] + w11[k] * gy11[k];
                float wfx = w00[k] * gx00[k] + w01[k] * gx01[k] +
                            w10[k] * gx10[k] + w11[k] * gx11[k];
                float dy = Y[k] - wfy;
                float dx = X[k] - wfx;
                a_dt += msk[k] * (sqrtf(dy * dy + 1e-9f) + sqrtf(dx * dx + 1e-9f));
                a_m += msk[k];
            }
        }
    }

    float r_sp = block_reduce_256(a_sp, smem);
    float r_dt = block_reduce_256(a_dt, smem);
    float r_m = block_reduce_256(a_m, smem);
    if (tid == 0) {
        atomicAdd(&acc[4 + plane], r_sp);
        if (do_temp) {
            int bp = b * (PPP - 1) + p;
            atomicAdd(&acc[20 + bp], r_dt);
            atomicAdd(&acc[52 + bp], r_m);
        }
    }
}

// ---------------- K1: bin (blocks 0..1023)  ||  flow part A ----------------
__global__ __launch_bounds__(256) void k1_bin_flow(
        const float* __restrict__ ev, const float* __restrict__ pol,
        const float* __restrict__ ts, float4* __restrict__ bucket,
        unsigned* __restrict__ gcnt, const float* __restrict__ flow,
        float* __restrict__ acc) {
    __shared__ unsigned ubuf[2 * TPB];
    __shared__ float smem[4];
    int tid = threadIdx.x;

    if (blockIdx.x < NBIN) {
        // ---- bin: counting-sort events into per-tile buckets ----
        unsigned* hist = ubuf;
        unsigned* basebuf = ubuf + TPB;
        if (tid < TPB) hist[tid] = 0;
        __syncthreads();

        int start = blockIdx.x * 1024;
        int b = start >> 18;
        const float2* ev2 = (const float2*)ev;

        float yv[4], xv[4], vv[4];
        int tt[4];
        unsigned rr[4];
#pragma unroll
        for (int k = 0; k < 4; ++k) {
            int gidx = start + tid + k * 256;
            int n = gidx & (NN - 1);
            float2 e = ev2[gidx];
            float y = e.x, x = e.y;
            int iy = (int)floorf(y), ix = (int)floorf(x);
            int t = (iy / TH) * TXN + (ix / TW);
            float p0 = pol[((size_t)b * 4 * NN + n) * 2];
            float tsv = ts[(size_t)b * 4 * NN + n];
            float nt = 1.0f - fabsf(1.0f - tsv);
            float v = nt * nt;
            yv[k] = y; xv[k] = x;
            vv[k] = (p0 > 0.5f) ? v : -v;
            tt[k] = t;
            rr[k] = atomicAdd(&hist[t], 1u);
        }
        __syncthreads();
        if (tid < TPB) basebuf[tid] = atomicAdd(&gcnt[b * TPB + tid], hist[tid]);
        __syncthreads();

#pragma unroll
        for (int k = 0; k < 4; ++k) {
            unsigned slot = basebuf[tt[k]] + rr[k];
            if (slot < CAP)
                bucket[((size_t)(b * TPB + tt[k]) << CAPSHIFT) + slot] =
                    make_float4(yv[k], xv[k], vv[k], 0.0f);
        }
    } else {
        int s = blockIdx.x - NBIN;                    // 0..FU_A-1
        int g = (s & 7) * (FU_A / 8) + (s >> 3);      // XCD-chunked, bijective
        flow_work(g, flow, acc, smem);
    }
}

// ---------------- K2: tile_accum (blocks 0..639)  ||  flow part B ----------
__global__ __launch_bounds__(256) void k2_tile_flow(
        const float4* __restrict__ bucket, const unsigned* __restrict__ gcnt,
        float* __restrict__ bnd, float* __restrict__ halo,
        const float* __restrict__ flow, float* __restrict__ acc) {
    __shared__ float T[2][TH + 1][TW + 1];
    __shared__ float smem[4];
    int tid = threadIdx.x;

    if (blockIdx.x < NT) {
        int l = blockIdx.x;
        int b = l / TPB;
        int t = l - b * TPB;
        int row0 = (t / TXN) * TH;
        int col0 = (t % TXN) * TW;

        for (int i = tid; i < 2 * (TH + 1) * (TW + 1); i += 256) ((float*)T)[i] = 0.0f;
        __syncthreads();

        unsigned cnt = gcnt[l];
        if (cnt > CAP) cnt = CAP;
        const float4* bk = bucket + ((size_t)l << CAPSHIFT);

        for (unsigned j = tid; j < cnt; j += 256) {
            float4 r = bk[j];
            float y = r.x, x = r.y, v = r.z;
            float fyf = floorf(y), fxf = floorf(x);
            int ly = (int)fyf - row0;
            int lx = (int)fxf - col0;
            unsigned u = __float_as_uint(v);
            int plane = u >> 31;
            float a = __uint_as_float(u & 0x7fffffffu);
            float wy1 = y - fyf, wy0 = 1.0f - wy1;
            float wx1 = x - fxf, wx0 = 1.0f - wx1;
            float* Tp = &T[plane][ly][lx];
            atomicAdd(Tp, a * wy0 * wx0);
            atomicAdd(Tp + 1, a * wy0 * wx1);
            atomicAdd(Tp + (TW + 1), a * wy1 * wx0);
            atomicAdd(Tp + (TW + 2), a * wy1 * wx1);
        }
        __syncthreads();

        // focus over final cells: rows 1..TH-1, cols 1..TW-1
        float a1 = 0.0f, a2 = 0.0f;
        for (int i = tid; i < (TH - 1) * (TW - 1); i += 256) {
            int r = 1 + i / (TW - 1);
            int c = 1 + i % (TW - 1);
            float ps = T[0][r][c], ns = T[1][r][c];
            a1 += ps * ps + ns * ns;
            a2 += (ps > 0.0f || ns > 0.0f) ? 1.0f : 0.0f;
        }

        // boundary cells: row 0 (TW cols), col 0 (rows 1..TH-1)
        for (int i = tid; i < 2 * BNDC; i += 256) {
            int p = i / BNDC, q = i - p * BNDC;
            float v = (q < TW) ? T[p][0][q] : T[p][q - (TW - 1)][0];
            bnd[((size_t)l * 2 + p) * BND_PITCH + q] = v;
        }
        // halo strips: row TH (TW+1 cols incl corner), col TW (rows 0..TH-1)
        for (int i = tid; i < 2 * HALC; i += 256) {
            int p = i / HALC, q = i - p * HALC;
            float v = (q < TW + 1) ? T[p][TH][q] : T[p][q - (TW + 1)][TW];
            halo[((size_t)l * 2 + p) * HALO_PITCH + q] = v;
        }

        float r1 = block_reduce_256(a1, smem);
        float r2 = block_reduce_256(a2, smem);
        if (tid == 0) {
            atomicAdd(&acc[b], r1);
            atomicAdd(&acc[32 + b], r2);
        }
    } else {
        int s = blockIdx.x - NT;                      // 0..FU_B-1
        int g = FU_A + (s & 7) * (FU_B / 8) + (s >> 3);
        flow_work(g, flow, acc, smem);
    }
}

// ---------------- K3: boundary merge + last-block finalize -----------------
__global__ void merge_finalize(const float* __restrict__ bnd,
                               const float* __restrict__ halo,
                               float* __restrict__ acc,
                               unsigned* __restrict__ ticket,
                               float* __restrict__ out) {
    __shared__ float smem[4];
    __shared__ unsigned is_last;
    int l = blockIdx.x;
    int tid = threadIdx.x;
    int b = l / TPB;
    int t = l - b * TPB;
    int ty = t / TXN, tx = t - ty * TXN;

    float a1 = 0.0f, a2 = 0.0f;
    if (tid < BNDC) {
        float v[2];
#pragma unroll
        for (int p = 0; p < 2; ++p) {
            float s = bnd[((size_t)l * 2 + p) * BND_PITCH + tid];
            if (tid < TW) {
                if (ty > 0) s += halo[((size_t)(l - TXN) * 2 + p) * HALO_PITCH + tid];
                if (tid == 0) {
                    if (ty > 0 && tx > 0)
                        s += halo[((size_t)(l - TXN - 1) * 2 + p) * HALO_PITCH + TW];
                    if (tx > 0)
                        s += halo[((size_t)(l - 1) * 2 + p) * HALO_PITCH + (TW + 1) + 0];
                }
            } else {
                int r = tid - (TW - 1);  // 1..TH-1
                if (tx > 0) s += halo[((size_t)(l - 1) * 2 + p) * HALO_PITCH + (TW + 1) + r];
            }
            v[p] = s;
        }
        a1 = v[0] * v[0] + v[1] * v[1];
        a2 = (v[0] > 0.0f || v[1] > 0.0f) ? 1.0f : 0.0f;
    }
    float r1 = block_reduce_256(a1, smem);
    float r2 = block_reduce_256(a2, smem);
    if (tid == 0) {
        atomicAdd(&acc[b], r1);
        atomicAdd(&acc[32 + b], r2);
        __threadfence();
        is_last = (atomicAdd(ticket, 1u) == NT - 1) ? 1u : 0u;
    }
    __syncthreads();
    if (tid == 0 && is_last) {
        float loss = 0.0f;
        for (int bb = 0; bb < BB; ++bb) loss += acc[bb] / (acc[32 + bb] + 1e-9f);
        for (int r = 4; r < 20; ++r) loss += acc[r];
        float tl = 0.0f;
        for (int r = 20; r < 32; ++r) tl += acc[r] / (acc[32 + r] + 1e-9f);
        loss += tl / (float)(PPP - 1);
        out[0] = loss;
    }
}

extern "C" void kernel_launch(void* const* d_in, const int* in_sizes, int n_in,
                              void* d_out, int out_size, void* d_ws, size_t ws_size,
                              hipStream_t stream) {
    const float* ev = (const float*)d_in[0];    // (B,N,2)
    const float* pol = (const float*)d_in[1];   // (B,4N,2)
    const float* ts = (const float*)d_in[2];    // (B,4N,1)
    const float* flow = (const float*)d_in[3];  // (B,P,2,H,W)
    float* out = (float*)d_out;
    float* ws = (float*)d_ws;

    float* acc = ws;                              // [0,64)
    unsigned* ticket = (unsigned*)(ws + 64);      // [64,65)
    unsigned* gcnt = (unsigned*)(ws + 68);        // [68,708)
    float4* bucket = (float4*)(ws + 768);         // 16B-aligned
    float* bnd = (float*)(bucket + ((size_t)NT << CAPSHIFT));
    float* halo = bnd + (size_t)NT * 2 * BND_PITCH;

    hipMemsetAsync(ws, 0, 3072, stream);  // acc + ticket + gcnt (+pad)

    k1_bin_flow<<<NBIN + FU_A, 256, 0, stream>>>(ev, pol, ts, bucket, gcnt, flow, acc);
    k2_tile_flow<<<NT + FU_B, 256, 0, stream>>>(bucket, gcnt, bnd, halo, flow, acc);
    merge_finalize<<<NT, 256, 0, stream>>>(bnd, halo, acc, ticket, out);
}

// Round 9
// 129.626 us; speedup vs baseline: 1.2458x; 1.1216x over previous
//
#include <hip/hip_runtime.h>

#define HH 480
#define WW 640
#define BB 4
#define PPP 4
#define NN 262144
#define HWPX (HH * WW)

// scatter tiling: 24x80 tiles, 20 rows x 8 cols per batch
#define TH 24
#define TW 80
#define TXN 8                // tiles per row
#define TPB 160              // tiles per batch (20x8)
#define NT (BB * TPB)        // 640 tiles total
#define BNDC (TW + TH - 1)   // 103 boundary cells
#define HALC (TW + 1 + TH)   // 105 halo cells
#define BND_PITCH 104
#define HALO_PITCH 108
#define CAP 2048             // bucket capacity per tile (mean ~1638, ~10 sigma)
#define CAPSHIFT 11

#define NBIN 1024            // bin blocks (K1)
#define NSPAT 2400           // spatial units: 16 planes x 150 (K1)
#define NTEMPA 600           // temporal units in K1 (pairs 0..3)
#define NTEMPB 1200          // temporal units in K2 (pairs 4..11)

__device__ __forceinline__ float charb6(float a) { return sqrtf(a * a + 1e-6f); }

// ---------------- block reduce helper (256 threads) ----------------
__device__ __forceinline__ float block_reduce_256(float v, float* smem) {
#pragma unroll
    for (int off = 32; off > 0; off >>= 1) v += __shfl_down(v, off, 64);
    int lane = threadIdx.x & 63;
    int wid = threadIdx.x >> 6;
    if (lane == 0) smem[wid] = v;
    __syncthreads();
    float r = 0.0f;
    if (threadIdx.x == 0) r = smem[0] + smem[1] + smem[2] + smem[3];
    __syncthreads();
    return r;  // valid only on thread 0
}

// ---------------- Spatial work unit: 2048 px of one plane ----------------
__device__ void spat_work(int s, const float* __restrict__ flow,
                          float* __restrict__ acc, float* smem) {
    int tid = threadIdx.x;
    int plane = s / 150;
    int rem = s - plane * 150;

    const float* fx = flow + (size_t)(plane * 2) * HWPX;
    const float* fy = fx + HWPX;

    const float wdx = 1.0f / ((float)HH * (float)(WW - 1) * (float)PPP * 4.0f);
    const float wdy = 1.0f / ((float)(HH - 1) * (float)WW * (float)PPP * 4.0f);
    const float wdd = 1.0f / ((float)(HH - 1) * (float)(WW - 1) * (float)PPP * 4.0f);

    float a_sp = 0.0f;

#pragma unroll
    for (int q = 0; q < 2; ++q) {
        int off = rem * 2048 + q * 1024 + tid * 4;
        int h = off / WW;
        int c = off - h * WW;

        float mhe = (h < HH - 1) ? 1.0f : 0.0f;
        int ib = (h < HH - 1) ? off + WW : off;
        int ir = (c + 4 < WW) ? off + 4 : off + 3;
        int ibr = (c + 4 < WW) ? ib + 4 : ib + 3;

        float4 fxv = *(const float4*)(fx + off);
        float4 fyv = *(const float4*)(fy + off);
        float4 fxb = *(const float4*)(fx + ib);
        float4 fyb = *(const float4*)(fy + ib);
        float X[5] = {fxv.x, fxv.y, fxv.z, fxv.w, fx[ir]};
        float Y[5] = {fyv.x, fyv.y, fyv.z, fyv.w, fy[ir]};
        float XB[5] = {fxb.x, fxb.y, fxb.z, fxb.w, fx[ibr]};
        float YB[5] = {fyb.x, fyb.y, fyb.z, fyb.w, fy[ibr]};

#pragma unroll
        for (int k = 0; k < 4; ++k) {
            float mwe = (c + k < WW - 1) ? 1.0f : 0.0f;
            a_sp += mwe * wdx * (charb6(X[k] - X[k + 1]) + charb6(Y[k] - Y[k + 1]))
                  + mhe * wdy * (charb6(X[k] - XB[k]) + charb6(Y[k] - YB[k]))
                  + mhe * mwe * wdd * (charb6(X[k] - XB[k + 1]) + charb6(Y[k] - YB[k + 1])
                                     + charb6(XB[k] - X[k + 1]) + charb6(YB[k] - Y[k + 1]));
        }
    }

    float r_sp = block_reduce_256(a_sp, smem);
    if (tid == 0) atomicAdd(&acc[4 + plane], r_sp);
}

// ---------------- Temporal work unit: 2048 px of one plane-pair -----------
// Paired-column gather: one unaligned float2 covers corners (x0,x1).
// xl=min(x0,638), sel=x0-xl is exact for all in-bounds px; OOB px are masked.
__device__ void temp_work(int u, const float* __restrict__ flow,
                          float* __restrict__ acc, float* smem) {
    int tid = threadIdx.x;
    int pair = u / 150;        // 0..11
    int rem = u - pair * 150;
    int bb = pair / 3, pp = pair - bb * 3;
    int cp = bb * 4 + pp;      // cur plane id
    const float* fxc = flow + (size_t)(cp * 2) * HWPX;
    const float* fyc = fxc + HWPX;
    const float* fxn = fxc + 2 * HWPX;
    const float* fyn = fyc + 2 * HWPX;

    float a_dt = 0.0f, a_m = 0.0f;

#pragma unroll
    for (int q = 0; q < 2; ++q) {
        int off = rem * 2048 + q * 1024 + tid * 4;
        int h = off / WW;
        int c = off - h * WW;

        float4 xv = *(const float4*)(fxc + off);
        float4 yv = *(const float4*)(fyc + off);
        float X[4] = {xv.x, xv.y, xv.z, xv.w};
        float Y[4] = {yv.x, yv.y, yv.z, yv.w};

        float msk[4], w00[4], w01[4], w10[4], w11[4];
        int aA[4], aB[4], sel[4];
#pragma unroll
        for (int k = 0; k < 4; ++k) {
            float wy = (float)h + Y[k];
            float wx = (float)(c + k) + X[k];
            msk[k] = (wy >= 0.0f && wy <= (float)(HH - 1) &&
                      wx >= 0.0f && wx <= (float)(WW - 1)) ? 1.0f : 0.0f;
            float y0f = floorf(wy), x0f = floorf(wx);
            float fy1 = wy - y0f, fx1 = wx - x0f;
            float fy0 = 1.0f - fy1, fx0 = 1.0f - fx1;
            w00[k] = fy0 * fx0; w01[k] = fy0 * fx1;
            w10[k] = fy1 * fx0; w11[k] = fy1 * fx1;
            int y0 = (int)fminf(fmaxf(y0f, 0.0f), (float)(HH - 1));
            int y1 = (int)fminf(fmaxf(y0f + 1.0f, 0.0f), (float)(HH - 1));
            int x0 = (int)fminf(fmaxf(x0f, 0.0f), (float)(WW - 1));
            int xl = min(x0, WW - 2);
            sel[k] = x0 - xl;
            aA[k] = y0 * WW + xl;
            aB[k] = y1 * WW + xl;
        }
        float2 A[4], B[4], C[4], D[4];
#pragma unroll
        for (int k = 0; k < 4; ++k) {
            __builtin_memcpy(&A[k], fyn + aA[k], 8);
            __builtin_memcpy(&B[k], fyn + aB[k], 8);
        }
#pragma unroll
        for (int k = 0; k < 4; ++k) {
            __builtin_memcpy(&C[k], fxn + aA[k], 8);
            __builtin_memcpy(&D[k], fxn + aB[k], 8);
        }
#pragma unroll
        for (int k = 0; k < 4; ++k) {
            float a0 = sel[k] ? A[k].y : A[k].x;
            float b0 = sel[k] ? B[k].y : B[k].x;
            float c0 = sel[k] ? C[k].y : C[k].x;
            float d0 = sel[k] ? D[k].y : D[k].x;
            float wfy = w00[k] * a0 + w01[k] * A[k].y + w10[k] * b0 + w11[k] * B[k].y;
            float wfx = w00[k] * c0 + w01[k] * C[k].y + w10[k] * d0 + w11[k] * D[k].y;
            float dy = Y[k] - wfy, dx = X[k] - wfx;
            a_dt += msk[k] * (sqrtf(dy * dy + 1e-9f) + sqrtf(dx * dx + 1e-9f));
            a_m += msk[k];
        }
    }

    float r_dt = block_reduce_256(a_dt, smem);
    float r_m = block_reduce_256(a_m, smem);
    if (tid == 0) {
        atomicAdd(&acc[20 + pair], r_dt);
        atomicAdd(&acc[52 + pair], r_m);
    }
}

// ---------------- K1: bin || spatial || temporal-A -------------------------
__global__ __launch_bounds__(256, 4) void k1_kernel(
        const float* __restrict__ ev, const float* __restrict__ pol,
        const float* __restrict__ ts, float4* __restrict__ bucket,
        unsigned* __restrict__ gcnt, const float* __restrict__ flow,
        float* __restrict__ acc) {
    __shared__ unsigned ubuf[2 * TPB];
    __shared__ float smem[4];
    int tid = threadIdx.x;

    if (blockIdx.x < NBIN) {
        // ---- bin: counting-sort events into per-tile buckets ----
        unsigned* hist = ubuf;
        unsigned* basebuf = ubuf + TPB;
        if (tid < TPB) hist[tid] = 0;
        __syncthreads();

        int start = blockIdx.x * 1024;
        int b = start >> 18;
        const float2* ev2 = (const float2*)ev;

        float yv[4], xv[4], vv[4];
        int tt[4];
        unsigned rr[4];
#pragma unroll
        for (int k = 0; k < 4; ++k) {
            int gidx = start + tid + k * 256;
            int n = gidx & (NN - 1);
            float2 e = ev2[gidx];
            float y = e.x, x = e.y;
            int iy = (int)floorf(y), ix = (int)floorf(x);
            int t = (iy / TH) * TXN + (ix / TW);
            float p0 = pol[((size_t)b * 4 * NN + n) * 2];
            float tsv = ts[(size_t)b * 4 * NN + n];
            float nt = 1.0f - fabsf(1.0f - tsv);
            float v = nt * nt;
            yv[k] = y; xv[k] = x;
            vv[k] = (p0 > 0.5f) ? v : -v;
            tt[k] = t;
            rr[k] = atomicAdd(&hist[t], 1u);
        }
        __syncthreads();
        if (tid < TPB) basebuf[tid] = atomicAdd(&gcnt[b * TPB + tid], hist[tid]);
        __syncthreads();

#pragma unroll
        for (int k = 0; k < 4; ++k) {
            unsigned slot = basebuf[tt[k]] + rr[k];
            if (slot < CAP)
                bucket[((size_t)(b * TPB + tt[k]) << CAPSHIFT) + slot] =
                    make_float4(yv[k], xv[k], vv[k], 0.0f);
        }
    } else if (blockIdx.x < NBIN + NSPAT) {
        spat_work(blockIdx.x - NBIN, flow, acc, smem);
    } else {
        int i = blockIdx.x - (NBIN + NSPAT);          // 0..NTEMPA-1
        int u = (i & 7) * (NTEMPA / 8) + (i >> 3);    // XCD-chunked, bijective
        temp_work(u, flow, acc, smem);
    }
}

// ---------------- K2: tile_accum || temporal-B -----------------------------
__global__ __launch_bounds__(256, 4) void k2_kernel(
        const float4* __restrict__ bucket, const unsigned* __restrict__ gcnt,
        float* __restrict__ bnd, float* __restrict__ halo,
        const float* __restrict__ flow, float* __restrict__ acc) {
    __shared__ float T[2][TH + 1][TW + 1];
    __shared__ float smem[4];
    int tid = threadIdx.x;

    if (blockIdx.x < NT) {
        int l = blockIdx.x;
        int b = l / TPB;
        int t = l - b * TPB;
        int row0 = (t / TXN) * TH;
        int col0 = (t % TXN) * TW;

        for (int i = tid; i < 2 * (TH + 1) * (TW + 1); i += 256) ((float*)T)[i] = 0.0f;
        __syncthreads();

        unsigned cnt = gcnt[l];
        if (cnt > CAP) cnt = CAP;
        const float4* bk = bucket + ((size_t)l << CAPSHIFT);

        for (unsigned j = tid; j < cnt; j += 256) {
            float4 r = bk[j];
            float y = r.x, x = r.y, v = r.z;
            float fyf = floorf(y), fxf = floorf(x);
            int ly = (int)fyf - row0;
            int lx = (int)fxf - col0;
            unsigned u = __float_as_uint(v);
            int plane = u >> 31;
            float a = __uint_as_float(u & 0x7fffffffu);
            float wy1 = y - fyf, wy0 = 1.0f - wy1;
            float wx1 = x - fxf, wx0 = 1.0f - wx1;
            float* Tp = &T[plane][ly][lx];
            atomicAdd(Tp, a * wy0 * wx0);
            atomicAdd(Tp + 1, a * wy0 * wx1);
            atomicAdd(Tp + (TW + 1), a * wy1 * wx0);
            atomicAdd(Tp + (TW + 2), a * wy1 * wx1);
        }
        __syncthreads();

        // focus over final cells: rows 1..TH-1, cols 1..TW-1
        float a1 = 0.0f, a2 = 0.0f;
        for (int i = tid; i < (TH - 1) * (TW - 1); i += 256) {
            int r = 1 + i / (TW - 1);
            int c = 1 + i % (TW - 1);
            float ps = T[0][r][c], ns = T[1][r][c];
            a1 += ps * ps + ns * ns;
            a2 += (ps > 0.0f || ns > 0.0f) ? 1.0f : 0.0f;
        }

        // boundary cells: row 0 (TW cols), col 0 (rows 1..TH-1)
        for (int i = tid; i < 2 * BNDC; i += 256) {
            int p = i / BNDC, q = i - p * BNDC;
            float v = (q < TW) ? T[p][0][q] : T[p][q - (TW - 1)][0];
            bnd[((size_t)l * 2 + p) * BND_PITCH + q] = v;
        }
        // halo strips: row TH (TW+1 cols incl corner), col TW (rows 0..TH-1)
        for (int i = tid; i < 2 * HALC; i += 256) {
            int p = i / HALC, q = i - p * HALC;
            float v = (q < TW + 1) ? T[p][TH][q] : T[p][q - (TW + 1)][TW];
            halo[((size_t)l * 2 + p) * HALO_PITCH + q] = v;
        }

        float r1 = block_reduce_256(a1, smem);
        float r2 = block_reduce_256(a2, smem);
        if (tid == 0) {
            atomicAdd(&acc[b], r1);
            atomicAdd(&acc[32 + b], r2);
        }
    } else {
        int i = blockIdx.x - NT;                      // 0..NTEMPB-1
        int u = NTEMPA + (i & 7) * (NTEMPB / 8) + (i >> 3);
        temp_work(u, flow, acc, smem);
    }
}

// ---------------- K3: boundary merge + last-block finalize -----------------
__global__ void merge_finalize(const float* __restrict__ bnd,
                               const float* __restrict__ halo,
                               float* __restrict__ acc,
                               unsigned* __restrict__ ticket,
                               float* __restrict__ out) {
    __shared__ float smem[4];
    __shared__ unsigned is_last;
    int l = blockIdx.x;
    int tid = threadIdx.x;
    int b = l / TPB;
    int t = l - b * TPB;
    int ty = t / TXN, tx = t - ty * TXN;

    float a1 = 0.0f, a2 = 0.0f;
    if (tid < BNDC) {
        float v[2];
#pragma unroll
        for (int p = 0; p < 2; ++p) {
            float s = bnd[((size_t)l * 2 + p) * BND_PITCH + tid];
            if (tid < TW) {
                if (ty > 0) s += halo[((size_t)(l - TXN) * 2 + p) * HALO_PITCH + tid];
                if (tid == 0) {
                    if (ty > 0 && tx > 0)
                        s += halo[((size_t)(l - TXN - 1) * 2 + p) * HALO_PITCH + TW];
                    if (tx > 0)
                        s += halo[((size_t)(l - 1) * 2 + p) * HALO_PITCH + (TW + 1) + 0];
                }
            } else {
                int r = tid - (TW - 1);  // 1..TH-1
                if (tx > 0) s += halo[((size_t)(l - 1) * 2 + p) * HALO_PITCH + (TW + 1) + r];
            }
            v[p] = s;
        }
        a1 = v[0] * v[0] + v[1] * v[1];
        a2 = (v[0] > 0.0f || v[1] > 0.0f) ? 1.0f : 0.0f;
    }
    float r1 = block_reduce_256(a1, smem);
    float r2 = block_reduce_256(a2, smem);
    if (tid == 0) {
        atomicAdd(&acc[b], r1);
        atomicAdd(&acc[32 + b], r2);
        __threadfence();
        is_last = (atomicAdd(ticket, 1u) == NT - 1) ? 1u : 0u;
    }
    __syncthreads();
    if (tid == 0 && is_last) {
        float loss = 0.0f;
        for (int bb = 0; bb < BB; ++bb) loss += acc[bb] / (acc[32 + bb] + 1e-9f);
        for (int r = 4; r < 20; ++r) loss += acc[r];
        float tl = 0.0f;
        for (int r = 20; r < 32; ++r) tl += acc[r] / (acc[32 + r] + 1e-9f);
        loss += tl / (float)(PPP - 1);
        out[0] = loss;
    }
}

extern "C" void kernel_launch(void* const* d_in, const int* in_sizes, int n_in,
                              void* d_out, int out_size, void* d_ws, size_t ws_size,
                              hipStream_t stream) {
    const float* ev = (const float*)d_in[0];    // (B,N,2)
    const float* pol = (const float*)d_in[1];   // (B,4N,2)
    const float* ts = (const float*)d_in[2];    // (B,4N,1)
    const float* flow = (const float*)d_in[3];  // (B,P,2,H,W)
    float* out = (float*)d_out;
    float* ws = (float*)d_ws;

    float* acc = ws;                              // [0,64)
    unsigned* ticket = (unsigned*)(ws + 64);      // [64,65)
    unsigned* gcnt = (unsigned*)(ws + 68);        // [68,708)
    float4* bucket = (float4*)(ws + 768);         // 16B-aligned
    float* bnd = (float*)(bucket + ((size_t)NT << CAPSHIFT));
    float* halo = bnd + (size_t)NT * 2 * BND_PITCH;

    hipMemsetAsync(ws, 0, 3072, stream);  // acc + ticket + gcnt (+pad)

    k1_kernel<<<NBIN + NSPAT + NTEMPA, 256, 0, stream>>>(ev, pol, ts, bucket, gcnt, flow, acc);
    k2_kernel<<<NT + NTEMPB, 256, 0, stream>>>(bucket, gcnt, bnd, halo, flow, acc);
    merge_finalize<<<NT, 256, 0, stream>>>(bnd, halo, acc, ticket, out);
}